// Round 5
// baseline (96.219 us; speedup 1.0000x reference)
//
#include <hip/hip_runtime.h>
#include <hip/hip_bf16.h>
#include <math.h>

typedef __attribute__((ext_vector_type(8))) short short8;
typedef __attribute__((ext_vector_type(4))) float floatx4;

static __device__ __forceinline__ unsigned short bfbits(float f) {
    __hip_bfloat16 h = __float2bfloat16(f);
    unsigned short u;
    __builtin_memcpy(&u, &h, 2);
    return u;
}
static __device__ __forceinline__ unsigned pack2(float lo, float hi) {
    return (unsigned)bfbits(lo) | ((unsigned)bfbits(hi) << 16);
}

// ================= kernel 1: Bt transpose + bw convert + out zero =================
// ws layout: Bt bf16 [1152][128] at offset 0 (rows j<1024 = sw cols; 1024+o = bw rows)
__global__ __launch_bounds__(256) void kan_prep(
    const float* __restrict__ bw, const float* __restrict__ sw,
    unsigned char* __restrict__ ws, float* __restrict__ out)
{
    __shared__ float buf[128 * 65];              // padded: conflict-free transpose
    __hip_bfloat16* Bt = (__hip_bfloat16*)ws;
    const int blk = blockIdx.x;
    const int tid = threadIdx.x;

    if (blk < 16) {                              // transpose j-range [64blk, 64blk+64)
        const int a  = tid >> 1;
        const int jh = (tid & 1) * 32;
        const float* src = sw + a * 1024 + blk * 64 + jh;
        float* dst = buf + a * 65 + jh;
#pragma unroll
        for (int i = 0; i < 32; ++i) dst[i] = src[i];   // coalesced global read
        __syncthreads();
        const int jl = tid >> 2;
        const int aq = (tid & 3) * 32;
        unsigned p[16];
#pragma unroll
        for (int i = 0; i < 16; ++i)
            p[i] = pack2(buf[(aq + 2*i) * 65 + jl], buf[(aq + 2*i + 1) * 65 + jl]);
        uint4* o = (uint4*)(Bt + (blk * 64 + jl) * 128 + aq);
        o[0] = make_uint4(p[0], p[1], p[2], p[3]);
        o[1] = make_uint4(p[4], p[5], p[6], p[7]);
        o[2] = make_uint4(p[8], p[9], p[10], p[11]);
        o[3] = make_uint4(p[12], p[13], p[14], p[15]);
    } else if (blk < 18) {                       // Bt[1024+o][a] = bf16(bw[o][a])
        int base = (blk - 16) * 8192 + tid * 32;
        unsigned p[16];
#pragma unroll
        for (int i = 0; i < 8; ++i) {
            float4 v = *(const float4*)(bw + base + i * 4);
            p[2*i]     = pack2(v.x, v.y);
            p[2*i + 1] = pack2(v.z, v.w);
        }
        uint4* o = (uint4*)(Bt + 1024 * 128 + base);
#pragma unroll
        for (int i = 0; i < 4; ++i)
            o[i] = make_uint4(p[4*i], p[4*i+1], p[4*i+2], p[4*i+3]);
    } else {                                     // zero out (atomic target)
        int base = (blk - 18) * 8192 + tid * 32;
        float4 z = make_float4(0.f, 0.f, 0.f, 0.f);
#pragma unroll
        for (int i = 0; i < 8; ++i) *(float4*)(out + base + i * 4) = z;
    }
}

// ================= kernel 2: fused basis + GEMM chunks + in-LDS gather =================
#define SB_STR 136    // bf16; pad -> frag ds_read_b128 2-way (free)
#define SP_STR 136
#define ST_STR 68     // fp32
#define SC_STR 132

__global__ __launch_bounds__(256) void kan_main(
    const float* __restrict__ x,
    const unsigned char* __restrict__ ws,
    float* __restrict__ out)
{
    __shared__ __hip_bfloat16 sP[5 * 16 * SP_STR];   // A-tiles: P0..P3, S
    __shared__ __hip_bfloat16 sB[64 * SB_STR];       // B chunk (padded)
    __shared__ float sT[16 * ST_STR];                // T chunk 16x64
    __shared__ unsigned char sC[16 * SC_STR];        // gather idx c

    const __hip_bfloat16* Bt = (const __hip_bfloat16*)ws;
    const int tid = threadIdx.x;
    const int nb  = blockIdx.x >> 2;
    const int s   = blockIdx.x & 3;
    const int n0  = nb * 16;
    const int c_beg = (s == 0) ? 0 : (s == 1) ? 5 : (s == 2) ? 9 : 14;
    const int c_end = (s == 0) ? 5 : (s == 1) ? 9 : (s == 2) ? 14 : 18;

    // ---- prologue: silu/u/c + basis for 16 rows x 128 feats ----
    {
        const int r  = tid >> 4;
        const int i0 = (tid & 15) * 8;
        float v[8];
        *(float4*)(v)     = *(const float4*)(x + (n0 + r) * 128 + i0);
        *(float4*)(v + 4) = *(const float4*)(x + (n0 + r) * 128 + i0 + 4);
        float A5[5][8];
        unsigned char cc8[8];
#pragma unroll
        for (int i = 0; i < 8; ++i) {
            float xv = v[i];
            float si = xv / (1.0f + expf(-xv));
            float xn = fminf(fmaxf(xv, -1.0f), 1.0f);
            float t  = (xn + 2.2f) / 0.4f;      // (xn - G0)/H, exact match to verified path
            float u  = t - floorf(t);
            int idx  = (int)floorf(t);
            idx = min(max(idx, 3), 7);
            cc8[i] = (unsigned char)(idx - 3);
            float u2 = u * u, u3 = u2 * u, om = 1.0f - u;
            A5[0][i] = om * om * om * (1.0f / 6.0f);
            A5[1][i] = 0.5f * u3 - u2 + (2.0f / 3.0f);
            A5[2][i] = -0.5f * u3 + 0.5f * u2 + 0.5f * u + (1.0f / 6.0f);
            A5[3][i] = u3 * (1.0f / 6.0f);
            A5[4][i] = si;
        }
#pragma unroll
        for (int g = 0; g < 5; ++g) {
            unsigned p0 = pack2(A5[g][0], A5[g][1]);
            unsigned p1 = pack2(A5[g][2], A5[g][3]);
            unsigned p2 = pack2(A5[g][4], A5[g][5]);
            unsigned p3 = pack2(A5[g][6], A5[g][7]);
            *(uint4*)(sP + (g * 16 + r) * SP_STR + i0) = make_uint4(p0, p1, p2, p3);
        }
        unsigned u0 = cc8[0] | (cc8[1] << 8) | (cc8[2] << 16) | (cc8[3] << 24);
        unsigned u1 = cc8[4] | (cc8[5] << 8) | (cc8[6] << 16) | (cc8[7] << 24);
        *(unsigned*)(sC + r * SC_STR + i0)     = u0;
        *(unsigned*)(sC + r * SC_STR + i0 + 4) = u1;
    }

    const int w = tid >> 6, l = tid & 63;
    const int m = l & 15, q = l >> 4;
    const int gn  = tid & 15;        // gather: n row
    const int go8 = tid >> 4;        // gather: o8 = o/8
    const int br   = tid >> 2;       // B staging: row 0..63
    const int bseg = (tid & 3) * 32; // B staging: bf16 col segment

    float racc[8] = {0.f, 0.f, 0.f, 0.f, 0.f, 0.f, 0.f, 0.f};

    // prefetch first chunk's B-tile into registers (coalesced dwordx4)
    uint4 breg[4];
    {
        const uint4* src = (const uint4*)(Bt + (c_beg * 64 + br) * 128 + bseg);
#pragma unroll
        for (int i = 0; i < 4; ++i) breg[i] = src[i];
    }

    short8 afrag[4];
    int cur_g = -1;

    for (int cc = c_beg; cc < c_end; ++cc) {
        // staged B -> padded sB (2-way bank pattern: free)
#pragma unroll
        for (int i = 0; i < 4; ++i)
            *(uint4*)(sB + br * SB_STR + bseg + i * 8) = breg[i];
        __syncthreads();   // sB ready; also covers prologue sP/sC on first iter

        if (cc + 1 < c_end) {        // prefetch next chunk while computing this one
            const uint4* src = (const uint4*)(Bt + ((cc + 1) * 64 + br) * 128 + bseg);
#pragma unroll
            for (int i = 0; i < 4; ++i) breg[i] = src[i];
        }

        const int g = (cc < 16) ? (cc >> 2) : 4;
        if (g != cur_g) {            // A-frags change only at b-group boundary
            cur_g = g;
#pragma unroll
            for (int kk = 0; kk < 4; ++kk)
                afrag[kk] = *(const short8*)(sP + (g * 16 + m) * SP_STR + q * 8 + kk * 32);
        }

        floatx4 acc = {0.f, 0.f, 0.f, 0.f};
#pragma unroll
        for (int kk = 0; kk < 4; ++kk) {
            short8 bfr = *(const short8*)(sB + (16 * w + m) * SB_STR + q * 8 + kk * 32);
            acc = __builtin_amdgcn_mfma_f32_16x16x32_bf16(afrag[kk], bfr, acc, 0, 0, 0);
        }
        // C/D layout: row = q*4+reg (n), col = m (j within wave tile)
#pragma unroll
        for (int r = 0; r < 4; ++r)
            sT[(q * 4 + r) * ST_STR + 16 * w + m] = acc[r];
        __syncthreads();   // sT ready

        // gather-accumulate this chunk's contribution
        const int j0 = cc * 64;
        if (cc < 16) {
            const int b    = cc >> 2;
            const int jrel = j0 & 255;
            const int ob0  = jrel >> 4;
            if (go8 >= ob0 && go8 < ob0 + 4) {
#pragma unroll
                for (int h = 0; h < 2; ++h) {
                    int oh  = 2 * go8 + h;
                    int c   = sC[gn * SC_STR + 32 * b + oh];
                    int rel = 8 * oh + c - jrel;
#pragma unroll
                    for (int ol = 0; ol < 4; ++ol)
                        racc[4 * h + ol] += sT[gn * ST_STR + rel + ol];
                }
            }
        } else {
            const int o0 = j0 - 1024;
            if (go8 >= (o0 >> 3) && go8 < (o0 >> 3) + 8) {
#pragma unroll
                for (int i = 0; i < 8; ++i)
                    racc[i] += sT[gn * ST_STR + 8 * go8 + i - o0];
            }
        }
        // no 3rd barrier: next iter writes sB only (disjoint from sT), and all
        // waves passed the sT barrier => prior sB frag reads complete.
    }

    // out was zeroed by kan_prep; 4 col-splits accumulate atomically
    float* op = out + (n0 + gn) * 128 + 8 * go8;
#pragma unroll
    for (int i = 0; i < 8; ++i) atomicAdd(op + i, racc[i]);
}

extern "C" void kernel_launch(void* const* d_in, const int* in_sizes, int n_in,
                              void* d_out, int out_size, void* d_ws, size_t ws_size,
                              hipStream_t stream) {
    const float* x  = (const float*)d_in[0];
    const float* bw = (const float*)d_in[1];
    const float* sw = (const float*)d_in[2];
    float* out = (float*)d_out;
    unsigned char* ws = (unsigned char*)d_ws;
    kan_prep<<<dim3(50),  dim3(256), 0, stream>>>(bw, sw, ws, out);
    kan_main<<<dim3(512), dim3(256), 0, stream>>>(x, ws, out);
}

// Round 6
// 71.262 us; speedup vs baseline: 1.3502x; 1.3502x over previous
//
#include <hip/hip_runtime.h>
#include <hip/hip_bf16.h>
#include <math.h>

typedef __attribute__((ext_vector_type(8))) short short8;
typedef __attribute__((ext_vector_type(4))) float floatx4;

static __device__ __forceinline__ unsigned short bfbits(float f) {
    __hip_bfloat16 h = __float2bfloat16(f);
    unsigned short u;
    __builtin_memcpy(&u, &h, 2);
    return u;
}
static __device__ __forceinline__ unsigned pack2(float lo, float hi) {
    return (unsigned)bfbits(lo) | ((unsigned)bfbits(hi) << 16);
}

// ================= kernel 1: Bt transpose + bw convert =================
// ws: Bt bf16 [1152][128] (rows j<1024 = sw cols; rows 1024+o = bw rows)
__global__ __launch_bounds__(256) void kan_prep(
    const float* __restrict__ bw, const float* __restrict__ sw,
    unsigned char* __restrict__ ws)
{
    __shared__ float buf[128 * 65];
    __hip_bfloat16* Bt = (__hip_bfloat16*)ws;
    const int blk = blockIdx.x;
    const int tid = threadIdx.x;

    if (blk < 16) {                              // transpose j-range [64blk, 64blk+64)
        const int a  = tid >> 1;
        const int jh = (tid & 1) * 32;
        const float* src = sw + a * 1024 + blk * 64 + jh;
        float* dst = buf + a * 65 + jh;
#pragma unroll
        for (int i = 0; i < 32; ++i) dst[i] = src[i];
        __syncthreads();
        const int jl = tid >> 2;
        const int aq = (tid & 3) * 32;
        unsigned p[16];
#pragma unroll
        for (int i = 0; i < 16; ++i)
            p[i] = pack2(buf[(aq + 2*i) * 65 + jl], buf[(aq + 2*i + 1) * 65 + jl]);
        uint4* o = (uint4*)(Bt + (blk * 64 + jl) * 128 + aq);
        o[0] = make_uint4(p[0], p[1], p[2], p[3]);
        o[1] = make_uint4(p[4], p[5], p[6], p[7]);
        o[2] = make_uint4(p[8], p[9], p[10], p[11]);
        o[3] = make_uint4(p[12], p[13], p[14], p[15]);
    } else {                                     // Bt[1024+o][a] = bf16(bw[o][a])
        int base = (blk - 16) * 8192 + tid * 32;
        unsigned p[16];
#pragma unroll
        for (int i = 0; i < 8; ++i) {
            float4 v = *(const float4*)(bw + base + i * 4);
            p[2*i]     = pack2(v.x, v.y);
            p[2*i + 1] = pack2(v.z, v.w);
        }
        uint4* o = (uint4*)(Bt + 1024 * 128 + base);
#pragma unroll
        for (int i = 0; i < 4; ++i)
            o[i] = make_uint4(p[4*i], p[4*i+1], p[4*i+2], p[4*i+3]);
    }
}

// ================= kernel 2: fused basis + GEMM + in-LDS gather, NO atomics =======
// block (nb, s): rows [16nb,16nb+16), output cols [32s, 32s+32).
// spline chunks {s, s+4, s+8, s+12} (b-group = loop index), base = Bt rows 1024+32s.
#define SB_STR 136    // bf16 row stride
#define SP_STR 136
#define ST_STR 68     // fp32 row stride
#define SC_STR 132

__global__ __launch_bounds__(256) void kan_main(
    const float* __restrict__ x,
    const unsigned char* __restrict__ ws,
    float* __restrict__ out)
{
    __shared__ __hip_bfloat16 sP[5 * 16 * SP_STR];
    __shared__ __hip_bfloat16 sB[2][64 * SB_STR];
    __shared__ float sT[2][16 * ST_STR];
    __shared__ unsigned char sC[16 * SC_STR];

    const __hip_bfloat16* Bt = (const __hip_bfloat16*)ws;
    const int tid = threadIdx.x;
    const int nb  = blockIdx.x >> 2;
    const int s   = blockIdx.x & 3;
    const int n0  = nb * 16;

    // ---- prologue: silu/u/c + basis for 16 rows x 128 feats ----
    {
        const int r  = tid >> 4;
        const int i0 = (tid & 15) * 8;
        float v[8];
        *(float4*)(v)     = *(const float4*)(x + (n0 + r) * 128 + i0);
        *(float4*)(v + 4) = *(const float4*)(x + (n0 + r) * 128 + i0 + 4);
        float A5[5][8];
        unsigned char cc8[8];
#pragma unroll
        for (int i = 0; i < 8; ++i) {
            float xv = v[i];
            float si = xv / (1.0f + expf(-xv));
            float xn = fminf(fmaxf(xv, -1.0f), 1.0f);
            float t  = (xn + 2.2f) / 0.4f;
            float u  = t - floorf(t);
            int idx  = (int)floorf(t);
            idx = min(max(idx, 3), 7);
            cc8[i] = (unsigned char)(idx - 3);
            float u2 = u * u, u3 = u2 * u, om = 1.0f - u;
            A5[0][i] = om * om * om * (1.0f / 6.0f);
            A5[1][i] = 0.5f * u3 - u2 + (2.0f / 3.0f);
            A5[2][i] = -0.5f * u3 + 0.5f * u2 + 0.5f * u + (1.0f / 6.0f);
            A5[3][i] = u3 * (1.0f / 6.0f);
            A5[4][i] = si;
        }
#pragma unroll
        for (int g = 0; g < 5; ++g) {
            unsigned p0 = pack2(A5[g][0], A5[g][1]);
            unsigned p1 = pack2(A5[g][2], A5[g][3]);
            unsigned p2 = pack2(A5[g][4], A5[g][5]);
            unsigned p3 = pack2(A5[g][6], A5[g][7]);
            *(uint4*)(sP + (g * 16 + r) * SP_STR + i0) = make_uint4(p0, p1, p2, p3);
        }
        *(unsigned*)(sC + r * SC_STR + i0)     = cc8[0] | (cc8[1]<<8) | (cc8[2]<<16) | (cc8[3]<<24);
        *(unsigned*)(sC + r * SC_STR + i0 + 4) = cc8[4] | (cc8[5]<<8) | (cc8[6]<<16) | (cc8[7]<<24);
    }

    const int w = tid >> 6, l = tid & 63;
    const int m = l & 15, q = l >> 4;
    const int gn  = tid >> 4;        // gather/store: n row 0..15
    const int go2 = tid & 15;        // gather/store: o-pair (o = 32s + 2*go2)
    const int br   = tid >> 2;       // B staging row 0..63
    const int bseg = (tid & 3) * 32; // bf16 col segment

    float racc0 = 0.f, racc1 = 0.f;

    // prefetch chunk 0 (spline chunk s): rows [64s, 64s+64)
    uint4 breg[4];
    {
        const uint4* src = (const uint4*)(Bt + (s * 64 + br) * 128 + bseg);
#pragma unroll
        for (int i = 0; i < 4; ++i) breg[i] = src[i];
    }

    // t = 0..3: spline chunk cc = s + 4t (b-group = t); t = 4: base (32 cols)
    for (int t = 0; t < 5; ++t) {
        const int p = t & 1;
        // stage breg -> sB[p]
        if (t < 4 || tid < 128) {
#pragma unroll
            for (int i = 0; i < 4; ++i)
                *(uint4*)(&sB[p][br * SB_STR + bseg + i * 8]) = breg[i];
        }
        __syncthreads();   // sB[p] ready; sT[1-p] (chunk t-1) ready; sP/sC on t=0

        // prefetch next chunk
        if (t < 3) {
            const uint4* src = (const uint4*)(Bt + ((s + 4*(t+1)) * 64 + br) * 128 + bseg);
#pragma unroll
            for (int i = 0; i < 4; ++i) breg[i] = src[i];
        } else if (t == 3) {
            if (tid < 128) {
                const uint4* src = (const uint4*)(Bt + (1024 + s * 32 + br) * 128 + bseg);
#pragma unroll
                for (int i = 0; i < 4; ++i) breg[i] = src[i];
            }
        }

        // gather chunk t-1 from sT[1-p] (overlaps this chunk's MFMA)
        if (t > 0) {
            const int tb = t - 1;
            if (tb < 4) {
                int oh  = 8 * s + (go2 >> 1);
                int c   = sC[gn * SC_STR + 32 * tb + oh];
                int rel = 8 * (go2 >> 1) + c + 2 * (go2 & 1);
                racc0 += sT[1 - p][gn * ST_STR + rel];
                racc1 += sT[1 - p][gn * ST_STR + rel + 1];
            }
        }

        // MFMA: A-group g = t (P0..P3) or 4 (S for base)
        if (t < 4 || w < 2) {
            floatx4 acc = {0.f, 0.f, 0.f, 0.f};
#pragma unroll
            for (int kk = 0; kk < 4; ++kk) {
                short8 af  = *(const short8*)(sP + (t * 16 + m) * SP_STR + q * 8 + kk * 32);
                short8 bfr = *(const short8*)(&sB[p][(16 * w + m) * SB_STR + q * 8 + kk * 32]);
                acc = __builtin_amdgcn_mfma_f32_16x16x32_bf16(af, bfr, acc, 0, 0, 0);
            }
#pragma unroll
            for (int r = 0; r < 4; ++r)
                sT[p][(q * 4 + r) * ST_STR + 16 * w + m] = acc[r];
        }
    }
    __syncthreads();
    // gather base chunk (t=4, parity 0): out cols rel = 2*go2
    racc0 += sT[0][gn * ST_STR + 2 * go2];
    racc1 += sT[0][gn * ST_STR + 2 * go2 + 1];

    // exclusive ownership -> plain store (coalesced: go2 fastest)
    float2 o2 = make_float2(racc0, racc1);
    *(float2*)(out + (n0 + gn) * 128 + 32 * s + 2 * go2) = o2;
}

extern "C" void kernel_launch(void* const* d_in, const int* in_sizes, int n_in,
                              void* d_out, int out_size, void* d_ws, size_t ws_size,
                              hipStream_t stream) {
    const float* x  = (const float*)d_in[0];
    const float* bw = (const float*)d_in[1];
    const float* sw = (const float*)d_in[2];
    float* out = (float*)d_out;
    unsigned char* ws = (unsigned char*)d_ws;
    kan_prep<<<dim3(18),  dim3(256), 0, stream>>>(bw, sw, ws);
    kan_main<<<dim3(512), dim3(256), 0, stream>>>(x, ws, out);
}

// Round 7
// 63.487 us; speedup vs baseline: 1.5156x; 1.1225x over previous
//
#include <hip/hip_runtime.h>
#include <hip/hip_bf16.h>
#include <math.h>

typedef __attribute__((ext_vector_type(8))) short short8;
typedef __attribute__((ext_vector_type(4))) float floatx4;

static __device__ __forceinline__ unsigned short bfbits(float f) {
    __hip_bfloat16 h = __float2bfloat16(f);
    unsigned short u;
    __builtin_memcpy(&u, &h, 2);
    return u;
}
static __device__ __forceinline__ unsigned pack2(float lo, float hi) {
    return (unsigned)bfbits(lo) | ((unsigned)bfbits(hi) << 16);
}

// ---- LDS strides ----
#define SP_STR  136   // u16; A-tiles (basis/silu), b128 frag reads (R6-proven)
#define SBN_STR 76    // u16; natural [a][j] spline tile: 38-dword rows ->
                      //   frag u16 reads: q-alias 2-way (free), j' stride 6 (distinct)
#define SBB_STR 136   // u16; base bw tile [o][a], b128 frag reads (R6-proven)
#define ST_STR  68    // fp32
#define SC_STR  132

// Single fused kernel. block (nb, s): rows [16nb,16nb+16), out cols [32s,32s+32).
// Spline chunks {s, s+4, s+8, s+12} (b-group = t), base = bw rows [32s, 32s+32).
__global__ __launch_bounds__(256) void kan_fused(
    const float* __restrict__ x,
    const float* __restrict__ bw,
    const float* __restrict__ sw,
    float* __restrict__ out)
{
    __shared__ short sP[5 * 16 * SP_STR];
    __shared__ short sBn[2][128 * SBN_STR];
    __shared__ short sBb[32 * SBB_STR];
    __shared__ float sT[2][16 * ST_STR];
    __shared__ unsigned char sC[16 * SC_STR];

    const int tid = threadIdx.x;
    const int nb  = blockIdx.x >> 2;
    const int s   = blockIdx.x & 3;
    const int n0  = nb * 16;

    const int ar = tid >> 4;          // spline staging: row base 0..15
    const int sg = tid & 15;          // spline staging: 16B segment within 64-col chunk

    // ---- issue x loads, then chunk-0 sw prefetch (latency hides under basis VALU) ----
    const int r  = tid >> 4;
    const int i0 = (tid & 15) * 8;
    float v[8];
    *(float4*)(v)     = *(const float4*)(x + (n0 + r) * 128 + i0);
    *(float4*)(v + 4) = *(const float4*)(x + (n0 + r) * 128 + i0 + 4);

    float4 pre[8];
#pragma unroll
    for (int rr = 0; rr < 8; ++rr)    // chunk s: dense per-issue coalescing
        pre[rr] = *(const float4*)(sw + (ar + 16 * rr) * 1024 + s * 64 + sg * 4);

    // ---- prologue: silu/u/c + basis for 16 rows x 128 feats ----
    {
        float A5[5][8];
        unsigned char cc8[8];
#pragma unroll
        for (int i = 0; i < 8; ++i) {
            float xv = v[i];
            float si = xv / (1.0f + expf(-xv));
            float xn = fminf(fmaxf(xv, -1.0f), 1.0f);
            float t  = (xn + 2.2f) / 0.4f;     // (xn - G0)/H, bit-exact vs verified path
            float u  = t - floorf(t);
            int idx  = (int)floorf(t);
            idx = min(max(idx, 3), 7);
            cc8[i] = (unsigned char)(idx - 3);
            float u2 = u * u, u3 = u2 * u, om = 1.0f - u;
            A5[0][i] = om * om * om * (1.0f / 6.0f);
            A5[1][i] = 0.5f * u3 - u2 + (2.0f / 3.0f);
            A5[2][i] = -0.5f * u3 + 0.5f * u2 + 0.5f * u + (1.0f / 6.0f);
            A5[3][i] = u3 * (1.0f / 6.0f);
            A5[4][i] = si;
        }
#pragma unroll
        for (int g = 0; g < 5; ++g) {
            unsigned p0 = pack2(A5[g][0], A5[g][1]);
            unsigned p1 = pack2(A5[g][2], A5[g][3]);
            unsigned p2 = pack2(A5[g][4], A5[g][5]);
            unsigned p3 = pack2(A5[g][6], A5[g][7]);
            *(uint4*)(&sP[(g * 16 + r) * SP_STR + i0]) = make_uint4(p0, p1, p2, p3);
        }
        *(unsigned*)(&sC[r * SC_STR + i0])     = cc8[0] | (cc8[1]<<8) | (cc8[2]<<16) | (cc8[3]<<24);
        *(unsigned*)(&sC[r * SC_STR + i0 + 4]) = cc8[4] | (cc8[5]<<8) | (cc8[6]<<16) | (cc8[7]<<24);
    }

    const int w = tid >> 6, l = tid & 63;
    const int m = l & 15, q = l >> 4;
    const int gn  = tid >> 4;         // gather/store: n row 0..15
    const int go2 = tid & 15;         // gather/store: o-pair

    uint2 pk[8];
#pragma unroll
    for (int rr = 0; rr < 8; ++rr)
        pk[rr] = make_uint2(pack2(pre[rr].x, pre[rr].y), pack2(pre[rr].z, pre[rr].w));

    float racc0 = 0.f, racc1 = 0.f;
    float4 bpre[4];

    // ---- t = 0..3: spline chunk cc = s + 4t (b-group = t) ----
#pragma unroll
    for (int t = 0; t < 4; ++t) {
        const int p = t & 1;
#pragma unroll
        for (int rr = 0; rr < 8; ++rr)
            *(uint2*)(&sBn[p][(ar + 16 * rr) * SBN_STR + sg * 4]) = pk[rr];
        __syncthreads();   // sBn[p] ready; sT[1-p] ready; sP/sC on t=0

        if (t < 3) {
#pragma unroll
            for (int rr = 0; rr < 8; ++rr)
                pre[rr] = *(const float4*)(sw + (ar + 16 * rr) * 1024 + (s + 4 * (t + 1)) * 64 + sg * 4);
        } else {
#pragma unroll
            for (int i = 0; i < 4; ++i) {   // base: bw rows [32s,32s+32), dense coalesced
                int e = i * 256 + tid;
                bpre[i] = *(const float4*)(bw + (32 * s + (e >> 5)) * 128 + (e & 31) * 4);
            }
        }

        // gather chunk t-1 from sT[1-p] (overlaps this chunk's MFMA)
        if (t > 0) {
            int oh  = 8 * s + (go2 >> 1);
            int c   = sC[gn * SC_STR + 32 * (t - 1) + oh];
            int rel = 8 * (go2 >> 1) + c + 2 * (go2 & 1);
            racc0 += sT[1 - p][gn * ST_STR + rel];
            racc1 += sT[1 - p][gn * ST_STR + rel + 1];
        }

        // MFMA: A = sP group t; B-frags from natural tile via u16 column reads
        floatx4 acc = {0.f, 0.f, 0.f, 0.f};
#pragma unroll
        for (int kk = 0; kk < 4; ++kk) {
            short8 af = *(const short8*)(&sP[(t * 16 + m) * SP_STR + q * 8 + kk * 32]);
            short8 bf;
#pragma unroll
            for (int j2 = 0; j2 < 8; ++j2)
                bf[j2] = sBn[p][(kk * 32 + q * 8 + j2) * SBN_STR + 16 * w + m];
            acc = __builtin_amdgcn_mfma_f32_16x16x32_bf16(af, bf, acc, 0, 0, 0);
        }
#pragma unroll
        for (int rr = 0; rr < 4; ++rr)
            sT[p][(q * 4 + rr) * ST_STR + 16 * w + m] = acc[rr];

        if (t < 3) {
#pragma unroll
            for (int rr = 0; rr < 8; ++rr)
                pk[rr] = make_uint2(pack2(pre[rr].x, pre[rr].y), pack2(pre[rr].z, pre[rr].w));
        }
    }

    // ---- base chunk: stage bw tile, gather t=3, base MFMA ----
#pragma unroll
    for (int i = 0; i < 4; ++i) {
        int e = i * 256 + tid;
        *(uint2*)(&sBb[(e >> 5) * SBB_STR + (e & 31) * 4]) =
            make_uint2(pack2(bpre[i].x, bpre[i].y), pack2(bpre[i].z, bpre[i].w));
    }
    __syncthreads();   // sBb ready; sT[1] (t=3) ready; sT[0] gathers (t=2) complete

    {   // gather chunk t=3 from sT[1]
        int oh  = 8 * s + (go2 >> 1);
        int c   = sC[gn * SC_STR + 32 * 3 + oh];
        int rel = 8 * (go2 >> 1) + c + 2 * (go2 & 1);
        racc0 += sT[1][gn * ST_STR + rel];
        racc1 += sT[1][gn * ST_STR + rel + 1];
    }

    if (w < 2) {       // 32 base cols: waves 0,1
        floatx4 acc = {0.f, 0.f, 0.f, 0.f};
#pragma unroll
        for (int kk = 0; kk < 4; ++kk) {
            short8 af = *(const short8*)(&sP[(4 * 16 + m) * SP_STR + q * 8 + kk * 32]);
            short8 bf = *(const short8*)(&sBb[(16 * w + m) * SBB_STR + q * 8 + kk * 32]);
            acc = __builtin_amdgcn_mfma_f32_16x16x32_bf16(af, bf, acc, 0, 0, 0);
        }
#pragma unroll
        for (int rr = 0; rr < 4; ++rr)
            sT[0][(q * 4 + rr) * ST_STR + 16 * w + m] = acc[rr];
    }
    __syncthreads();

    racc0 += sT[0][gn * ST_STR + 2 * go2];
    racc1 += sT[0][gn * ST_STR + 2 * go2 + 1];

    *(float2*)(out + (n0 + gn) * 128 + 32 * s + 2 * go2) = make_float2(racc0, racc1);
}

extern "C" void kernel_launch(void* const* d_in, const int* in_sizes, int n_in,
                              void* d_out, int out_size, void* d_ws, size_t ws_size,
                              hipStream_t stream) {
    const float* x  = (const float*)d_in[0];
    const float* bw = (const float*)d_in[1];
    const float* sw = (const float*)d_in[2];
    float* out = (float*)d_out;
    kan_fused<<<dim3(512), dim3(256), 0, stream>>>(x, bw, sw, out);
}